// Round 2
// baseline (233.409 us; speedup 1.0000x reference)
//
#include <hip/hip_runtime.h>

#define NKEYS 64
#define UNROLL 4

// out[i] = t[x[i]] where t is a 64-entry table derived from (keys, b):
//   t[v] = b[k] if keys[k] == (float)v for integral v in [0,64), else 0.
//
// v3: direct LDS table lookup (64-entry table = max 2-way bank aliasing = free),
//     4x unrolled block-uniform fast path -> 4 coalesced 1KB loads in flight
//     per wave (MLP x4), nt stores for the write-once output, 2048-block
//     grid-stride.
__global__ __launch_bounds__(256) void sel_xform_kernel(
    const int4* __restrict__ in,
    const float* __restrict__ b,
    const float* __restrict__ keys,
    float4* __restrict__ out,
    int nvec, int ntail, const int* __restrict__ in_tail, float* __restrict__ out_tail)
{
    __shared__ float t[NKEYS];
    const int tid = threadIdx.x;
    if (tid < NKEYS) t[tid] = 0.0f;
    __syncthreads();
    if (tid < NKEYS) {
        const float kv = keys[tid];
        const int iv = (int)kv;
        if ((float)iv == kv && iv >= 0 && iv < NKEYS) {
            t[iv] = b[tid];   // keys are unique -> no write race
        }
    }
    __syncthreads();

    typedef float __attribute__((ext_vector_type(4))) f32x4;
    const int B = blockDim.x;                 // 256
    const int chunk = gridDim.x * B * UNROLL; // elements per grid pass

    // Branch-free table lookup: read t[v&63] (any LDS address is in-bounds),
    // then select 0 for out-of-range values. Compiler emits ds_read + cndmask.
    auto lut4 = [&](int4 v) -> float4 {
        const float rx = t[v.x & 63];
        const float ry = t[v.y & 63];
        const float rz = t[v.z & 63];
        const float rw = t[v.w & 63];
        float4 o;
        o.x = ((unsigned)v.x < NKEYS) ? rx : 0.0f;
        o.y = ((unsigned)v.y < NKEYS) ? ry : 0.0f;
        o.z = ((unsigned)v.z < NKEYS) ? rz : 0.0f;
        o.w = ((unsigned)v.w < NKEYS) ? rw : 0.0f;
        return o;
    };

    for (int base = blockIdx.x * B * UNROLL; base < nvec; base += chunk) {
        if (base + UNROLL * B <= nvec) {
            // Fast path (block-uniform condition, no divergence): issue all 4
            // coalesced loads back-to-back so 4KB/wave is in flight at once.
            const int i0 = base + tid;
            const int4 v0 = in[i0];
            const int4 v1 = in[i0 + B];
            const int4 v2 = in[i0 + 2 * B];
            const int4 v3 = in[i0 + 3 * B];

            const float4 o0 = lut4(v0);
            const float4 o1 = lut4(v1);
            const float4 o2 = lut4(v2);
            const float4 o3 = lut4(v3);

            // Output is write-once, never re-read: nt store keeps it from
            // evicting the input stream out of the 256MB L3.
            __builtin_nontemporal_store(*reinterpret_cast<const f32x4*>(&o0),
                                        reinterpret_cast<f32x4*>(&out[i0]));
            __builtin_nontemporal_store(*reinterpret_cast<const f32x4*>(&o1),
                                        reinterpret_cast<f32x4*>(&out[i0 + B]));
            __builtin_nontemporal_store(*reinterpret_cast<const f32x4*>(&o2),
                                        reinterpret_cast<f32x4*>(&out[i0 + 2 * B]));
            __builtin_nontemporal_store(*reinterpret_cast<const f32x4*>(&o3),
                                        reinterpret_cast<f32x4*>(&out[i0 + 3 * B]));
        } else {
            // Ragged last chunk: per-element guards.
            for (int j = 0; j < UNROLL; ++j) {
                const int i = base + j * B + tid;
                if (i < nvec) {
                    const float4 o = lut4(in[i]);
                    __builtin_nontemporal_store(*reinterpret_cast<const f32x4*>(&o),
                                                reinterpret_cast<f32x4*>(&out[i]));
                }
            }
        }
    }

    // Scalar tail (n % 4 elements), handled by the first few threads of block 0.
    if (blockIdx.x == 0 && tid < ntail) {
        const int v = in_tail[tid];
        out_tail[tid] = ((unsigned)v < NKEYS) ? t[v] : 0.0f;
    }
}

extern "C" void kernel_launch(void* const* d_in, const int* in_sizes, int n_in,
                              void* d_out, int out_size, void* d_ws, size_t ws_size,
                              hipStream_t stream) {
    const int*   x    = (const int*)d_in[0];     // inputs, int32, [8,4096,1024]
    const float* b    = (const float*)d_in[1];   // per-key bias, [64]
    const float* keys = (const float*)d_in[2];   // sorted unique keys, [64]
    float* out = (float*)d_out;

    const int n    = in_sizes[0];
    const int nvec = n >> 2;        // int4 / float4 groups
    const int ntail = n & 3;

    const int block = 256;
    // 2048 blocks = 8 blocks/CU: full occupancy at this VGPR count, and the
    // 4x-unrolled grid-stride covers 8.39M vec4 in exactly 4 passes.
    int grid = (nvec + block * UNROLL - 1) / (block * UNROLL);
    if (grid > 2048) grid = 2048;
    if (grid < 1) grid = 1;

    sel_xform_kernel<<<grid, block, 0, stream>>>(
        (const int4*)x, b, keys, (float4*)out,
        nvec, ntail, x + (nvec << 2), out + (nvec << 2));
}

// Round 4
// 233.024 us; speedup vs baseline: 1.0017x; 1.0017x over previous
//
#include <hip/hip_runtime.h>

#define NKEYS 64
#define UNROLL 4

// out[i] = t[x[i]] where t is a 64-entry table derived from (keys, b):
//   t[v] = b[k] if keys[k] == (float)v for integral v in [0,64), else 0.
//
// v4 (resubmit after infra failure): like v3 (direct LDS lookup, 4x unrolled
//     uniform fast path, 2048-block grid-stride) but with DEFAULT write-back
//     stores instead of nontemporal. The 134MB output fits in the 256MB
//     Infinity Cache: write-back lets the store burst land in L2/L3 at cache
//     BW and drain to HBM off the kernel's critical path. nt stores forced
//     all 134MB through HBM synchronously (round-1 counters: WRITE_SIZE ==
//     full output size) and were the regression vs the round-0 baseline.
__global__ __launch_bounds__(256) void sel_xform_kernel(
    const int4* __restrict__ in,
    const float* __restrict__ b,
    const float* __restrict__ keys,
    float4* __restrict__ out,
    int nvec, int ntail, const int* __restrict__ in_tail, float* __restrict__ out_tail)
{
    __shared__ float t[NKEYS];
    const int tid = threadIdx.x;
    if (tid < NKEYS) t[tid] = 0.0f;
    __syncthreads();
    if (tid < NKEYS) {
        const float kv = keys[tid];
        const int iv = (int)kv;
        if ((float)iv == kv && iv >= 0 && iv < NKEYS) {
            t[iv] = b[tid];   // keys are unique -> no write race
        }
    }
    __syncthreads();

    const int B = blockDim.x;                 // 256
    const int chunk = gridDim.x * B * UNROLL; // elements per grid pass

    // Branch-free table lookup: read t[v&63] (any LDS address is in-bounds),
    // then select 0 for out-of-range values. 64-entry table spans 2 rows of
    // the 32 banks -> worst case 2-way aliasing, which is free (m136).
    auto lut4 = [&](int4 v) -> float4 {
        const float rx = t[v.x & 63];
        const float ry = t[v.y & 63];
        const float rz = t[v.z & 63];
        const float rw = t[v.w & 63];
        float4 o;
        o.x = ((unsigned)v.x < NKEYS) ? rx : 0.0f;
        o.y = ((unsigned)v.y < NKEYS) ? ry : 0.0f;
        o.z = ((unsigned)v.z < NKEYS) ? rz : 0.0f;
        o.w = ((unsigned)v.w < NKEYS) ? rw : 0.0f;
        return o;
    };

    for (int base = blockIdx.x * B * UNROLL; base < nvec; base += chunk) {
        if (base + UNROLL * B <= nvec) {
            // Fast path (block-uniform condition, no divergence): issue all 4
            // coalesced loads back-to-back so 4KB/wave is in flight at once.
            const int i0 = base + tid;
            const int4 v0 = in[i0];
            const int4 v1 = in[i0 + B];
            const int4 v2 = in[i0 + 2 * B];
            const int4 v3 = in[i0 + 3 * B];

            out[i0]         = lut4(v0);
            out[i0 + B]     = lut4(v1);
            out[i0 + 2 * B] = lut4(v2);
            out[i0 + 3 * B] = lut4(v3);
        } else {
            // Ragged last chunk: per-element guards (not hit for 8x4096x1024).
            for (int j = 0; j < UNROLL; ++j) {
                const int i = base + j * B + tid;
                if (i < nvec) {
                    out[i] = lut4(in[i]);
                }
            }
        }
    }

    // Scalar tail (n % 4 elements), handled by the first few threads of block 0.
    if (blockIdx.x == 0 && tid < ntail) {
        const int v = in_tail[tid];
        out_tail[tid] = ((unsigned)v < NKEYS) ? t[v] : 0.0f;
    }
}

extern "C" void kernel_launch(void* const* d_in, const int* in_sizes, int n_in,
                              void* d_out, int out_size, void* d_ws, size_t ws_size,
                              hipStream_t stream) {
    const int*   x    = (const int*)d_in[0];     // inputs, int32, [8,4096,1024]
    const float* b    = (const float*)d_in[1];   // per-key bias, [64]
    const float* keys = (const float*)d_in[2];   // sorted unique keys, [64]
    float* out = (float*)d_out;

    const int n    = in_sizes[0];
    const int nvec = n >> 2;        // int4 / float4 groups
    const int ntail = n & 3;

    const int block = 256;
    // 2048 blocks = 8 blocks/CU; with UNROLL=4 the 8.39M vec4 are covered in
    // exactly 4 grid passes with no ragged iterations.
    int grid = (nvec + block * UNROLL - 1) / (block * UNROLL);
    if (grid > 2048) grid = 2048;
    if (grid < 1) grid = 1;

    sel_xform_kernel<<<grid, block, 0, stream>>>(
        (const int4*)x, b, keys, (float4*)out,
        nvec, ntail, x + (nvec << 2), out + (nvec << 2));
}

// Round 5
// 221.513 us; speedup vs baseline: 1.0537x; 1.0520x over previous
//
#include <hip/hip_runtime.h>

#define NKEYS 64
#define UNROLL 4

typedef int   __attribute__((ext_vector_type(4))) i32x4;
typedef float __attribute__((ext_vector_type(4))) f32x4;

// out[i] = t[x[i]] where t is a 64-entry table derived from (keys, b):
//   t[v] = b[k] if keys[k] == (float)v for integral v in [0,64), else 0.
//
// v5: FULL streaming — nontemporal loads AND stores. Round-4 counters showed
//     the L3 in a thrash steady-state (FETCH == exactly half the input: the
//     256MiB L3 holds half of the 512MiB {in,out} working set, every line
//     allocated then evicted) with the kernel pinned at 2.5 TB/s while the
//     harness fill streams at 6.7 TB/s. nt on both sides takes the
//     allocate/evict path out entirely, matching the proven streaming regime.
//     Structure otherwise identical to v4 (direct LDS lookup, 4x unrolled
//     uniform fast path, 2048-block grid-stride, exactly 4 passes).
__global__ __launch_bounds__(256) void sel_xform_kernel(
    const i32x4* __restrict__ in,
    const float* __restrict__ b,
    const float* __restrict__ keys,
    f32x4* __restrict__ out,
    int nvec, int ntail, const int* __restrict__ in_tail, float* __restrict__ out_tail)
{
    __shared__ float t[NKEYS];
    const int tid = threadIdx.x;
    if (tid < NKEYS) t[tid] = 0.0f;
    __syncthreads();
    if (tid < NKEYS) {
        const float kv = keys[tid];
        const int iv = (int)kv;
        if ((float)iv == kv && iv >= 0 && iv < NKEYS) {
            t[iv] = b[tid];   // keys are unique -> no write race
        }
    }
    __syncthreads();

    const int B = blockDim.x;                 // 256
    const int chunk = gridDim.x * B * UNROLL; // elements per grid pass

    // Branch-free table lookup: read t[v&63] (any LDS address is in-bounds),
    // then select 0 for out-of-range values. 64-entry table spans 2 rows of
    // the 32 banks -> worst case 2-way aliasing, which is free (m136).
    auto lut4 = [&](i32x4 v) -> f32x4 {
        const float rx = t[v.x & 63];
        const float ry = t[v.y & 63];
        const float rz = t[v.z & 63];
        const float rw = t[v.w & 63];
        f32x4 o;
        o.x = ((unsigned)v.x < NKEYS) ? rx : 0.0f;
        o.y = ((unsigned)v.y < NKEYS) ? ry : 0.0f;
        o.z = ((unsigned)v.z < NKEYS) ? rz : 0.0f;
        o.w = ((unsigned)v.w < NKEYS) ? rw : 0.0f;
        return o;
    };

    for (int base = blockIdx.x * B * UNROLL; base < nvec; base += chunk) {
        if (base + UNROLL * B <= nvec) {
            // Fast path (block-uniform condition, no divergence): 4 coalesced
            // streaming loads in flight per wave, then 4 streaming stores.
            const int i0 = base + tid;
            const i32x4 v0 = __builtin_nontemporal_load(in + i0);
            const i32x4 v1 = __builtin_nontemporal_load(in + i0 + B);
            const i32x4 v2 = __builtin_nontemporal_load(in + i0 + 2 * B);
            const i32x4 v3 = __builtin_nontemporal_load(in + i0 + 3 * B);

            __builtin_nontemporal_store(lut4(v0), out + i0);
            __builtin_nontemporal_store(lut4(v1), out + i0 + B);
            __builtin_nontemporal_store(lut4(v2), out + i0 + 2 * B);
            __builtin_nontemporal_store(lut4(v3), out + i0 + 3 * B);
        } else {
            // Ragged last chunk: per-element guards (not hit for 8x4096x1024).
            for (int j = 0; j < UNROLL; ++j) {
                const int i = base + j * B + tid;
                if (i < nvec) {
                    const i32x4 v = __builtin_nontemporal_load(in + i);
                    __builtin_nontemporal_store(lut4(v), out + i);
                }
            }
        }
    }

    // Scalar tail (n % 4 elements), handled by the first few threads of block 0.
    if (blockIdx.x == 0 && tid < ntail) {
        const int v = in_tail[tid];
        out_tail[tid] = ((unsigned)v < NKEYS) ? t[v] : 0.0f;
    }
}

extern "C" void kernel_launch(void* const* d_in, const int* in_sizes, int n_in,
                              void* d_out, int out_size, void* d_ws, size_t ws_size,
                              hipStream_t stream) {
    const int*   x    = (const int*)d_in[0];     // inputs, int32, [8,4096,1024]
    const float* b    = (const float*)d_in[1];   // per-key bias, [64]
    const float* keys = (const float*)d_in[2];   // sorted unique keys, [64]
    float* out = (float*)d_out;

    const int n    = in_sizes[0];
    const int nvec = n >> 2;        // int4 / float4 groups
    const int ntail = n & 3;

    const int block = 256;
    // 2048 blocks = 8 blocks/CU; with UNROLL=4 the 8.39M vec4 are covered in
    // exactly 4 grid passes with no ragged iterations.
    int grid = (nvec + block * UNROLL - 1) / (block * UNROLL);
    if (grid > 2048) grid = 2048;
    if (grid < 1) grid = 1;

    sel_xform_kernel<<<grid, block, 0, stream>>>(
        (const i32x4*)x, b, keys, (f32x4*)out,
        nvec, ntail, x + (nvec << 2), out + (nvec << 2));
}